// Round 11
// baseline (5797.651 us; speedup 1.0000x reference)
//
#include <hip/hip_runtime.h>

// BI-LSTM (TF LSTMCell w/ projection), T=160 B=640 F=40 HID=768 PROJ=256, 3 layers x 2 dirs.
// R16: R10 (proven best, 5509us) + XCD-LOCALITY CHUNKED SWIZZLE only.
// Evidence: R6/R8/R11/R15 proved the gate is insensitive to LDS traffic, barrier count,
// and load latency; R13's cold-cache counters (FETCH 40MB + WRITE 28MB/step) show the cost
// is data movement through the L2-miss path. Root cause: with grid (24,5,6), XCD = id%8
// gives every XCD bx-residue strips of ALL 6 z's => ~6.3MB weights + ~3MB state through a
// 4MB L2 -> thrash within a launch and zero warmth across launches.
// Fix: 1-D grid + chunked mapping  xcd=id%8; r=xcd*90+id/8; z=r/120; bx=(r%120)/5; by=r%5.
// Each XCD covers <=2 z's, ~18 contiguous n-strips: weights/XCD 6.3->2.4MB, total ~6MB.
// Mapping is identical every launch -> weight strips + c-state chunks stay L2-warm across
// steps instead of round-tripping L3. Proj chunked the same way (240 = 8x30).
// Everything else is R10 verbatim: reg-lookahead K-loop, LDS-staged A+B, 2 barriers/iter,
// epilogue c/bias prefetch, two launches per step (all in-kernel sync variants lost).

typedef _Float16 h8 __attribute__((ext_vector_type(8)));
typedef float f4 __attribute__((ext_vector_type(4)));

#define T_STEPS 160
#define NB 640
#define HID 768
#define PROJ 256
#define NGATE 3072           // 4*HID

__device__ __forceinline__ float sigm(float x) { return 1.0f / (1.0f + __expf(-x)); }
__device__ __forceinline__ float tanh_fast(float x) { return 2.0f / (1.0f + __expf(-2.0f * x)) - 1.0f; }

struct GateArgs {
  const _Float16* A0[6];   // x-part source (X16 for l=0, prev-layer ring slot otherwise)
  const _Float16* A1[6];   // own h ring slot (h_{t-1} fw / h_{t+1} bw)
  const _Float16* Bw[6];   // WkT, gate-interleaved [3072][Kpad]
  const float*    bias[6];
  float*          cst[6];
  _Float16*       g[6];
  int w0[6];
  int lda0[6];
  int K[6];
  int act[6];
};

struct ProjArgs {
  const _Float16* G[6];    // [640][768] fp16
  const _Float16* Wp[6];   // [256][768] fp16 (B^T)
  _Float16* out[6];        // own ring write slot
  _Float16* out2[6];       // optional embed capture (layer 2, t in {0,159})
  int act[6];
};

// ---------------- gate GEMM: z = [x,h] @ WkT^T, fused bias+gates+c-update -> g ----------------
__global__ __launch_bounds__(256, 3) void gate_step(GateArgs args) {
  // chunked XCD-locality mapping: each XCD gets a contiguous chunk of the z-major space
  const int id = blockIdx.x;           // 0..719
  const int r = (id & 7) * 90 + (id >> 3);
  const int z = r / 120;
  const int q = r % 120;
  const int bx = q / 5;                // n-tile 0..23 (contiguous strips per XCD)
  const int by = q % 5;                // m-tile 0..4
  if (!args.act[z]) return;

  __shared__ __align__(16) char sm[36864];       // As 18KB | Bs 18KB; epilogue overlays zs
  _Float16 (*As)[72] = (_Float16(*)[72])sm;      // [128][72]
  _Float16 (*Bs)[72] = (_Float16(*)[72])(sm + 18432);
  float (*zs)[65] = (float(*)[65])sm;            // [128][65] f32 = 33.3KB

  const _Float16* A0 = args.A0[z];
  const _Float16* A1 = args.A1[z];
  const _Float16* Bw = args.Bw[z];
  const int w0 = args.w0[z], lda0 = args.lda0[z], K = args.K[z];
  const int n0 = bx * 128;
  const int m0 = by * 128;
  const int tid = threadIdx.x;
  const int lane = tid & 63;
  const int wv = tid >> 6;         // 0..3
  const int wm = (wv & 1) * 64;    // wave covers rows [wm, wm+64), cols [wn, wn+64)
  const int wn = (wv >> 1) * 64;

  // ---- epilogue-operand prefetch (addresses known from block/tid alone) ----
  const float* bias = args.bias[z];
  float* cstate = args.cst[z];
  const int uu = tid & 15;
  const int rbase = tid >> 4;
  float cpre[2][8];
  float bpre[2][4];
#pragma unroll
  for (int p = 0; p < 2; ++p) {
    const int u0 = (n0 + p * 64) >> 2;
#pragma unroll
    for (int gg = 0; gg < 4; ++gg)
      bpre[p][gg] = bias[gg * HID + u0 + uu];
#pragma unroll
    for (int it = 0; it < 8; ++it)
      cpre[p][it] = cstate[(size_t)(m0 + it * 16 + rbase) * HID + u0 + uu];
  }

  f4 acc[4][4] = {};

  const int lr = tid >> 3;          // 0..31 (handles rows lr + 32*r)
  const int lkg = (tid & 7) * 8;    // k-group 0,8,..,56

  // ---- prologue: stage k0=0 into registers ----
  h8 av[4], bv[4];
  {
    const int gk = lkg;
    if (gk < w0) {
#pragma unroll
      for (int rr = 0; rr < 4; ++rr)
        av[rr] = *(const h8*)(A0 + (size_t)(m0 + lr + 32 * rr) * lda0 + gk);
    } else {
#pragma unroll
      for (int rr = 0; rr < 4; ++rr)
        av[rr] = *(const h8*)(A1 + (size_t)(m0 + lr + 32 * rr) * 256 + (gk - w0));
    }
#pragma unroll
    for (int rr = 0; rr < 4; ++rr)
      bv[rr] = *(const h8*)(Bw + (size_t)(n0 + lr + 32 * rr) * K + gk);
  }

  for (int k0 = 0; k0 < K; k0 += 64) {
    __syncthreads();                 // prior iter's LDS readers done
#pragma unroll
    for (int rr = 0; rr < 4; ++rr) { // vmcnt wait here is for regs staged LAST iter (hidden)
      *(h8*)&As[lr + 32 * rr][lkg] = av[rr];
      *(h8*)&Bs[lr + 32 * rr][lkg] = bv[rr];
    }
    // issue NEXT iter's loads now; latency hides under this iter's MFMAs
    if (k0 + 64 < K) {
      const int gk = k0 + 64 + lkg;
      if (gk < w0) {
#pragma unroll
        for (int rr = 0; rr < 4; ++rr)
          av[rr] = *(const h8*)(A0 + (size_t)(m0 + lr + 32 * rr) * lda0 + gk);
      } else {
#pragma unroll
        for (int rr = 0; rr < 4; ++rr)
          av[rr] = *(const h8*)(A1 + (size_t)(m0 + lr + 32 * rr) * 256 + (gk - w0));
      }
#pragma unroll
      for (int rr = 0; rr < 4; ++rr)
        bv[rr] = *(const h8*)(Bw + (size_t)(n0 + lr + 32 * rr) * K + gk);
    }
    __syncthreads();
#pragma unroll
    for (int kk = 0; kk < 2; ++kk) {
      const int kq = ((lane >> 4) * 8) + kk * 32;
      h8 bf[4];
#pragma unroll
      for (int j = 0; j < 4; ++j)
        bf[j] = *(const h8*)&Bs[wn + (lane & 15) + 16 * j][kq];
#pragma unroll
      for (int i = 0; i < 4; ++i) {
        h8 af = *(const h8*)&As[wm + (lane & 15) + 16 * i][kq];
#pragma unroll
        for (int j = 0; j < 4; ++j)
          acc[i][j] = __builtin_amdgcn_mfma_f32_16x16x32_f16(af, bf[j], acc[i][j], 0, 0, 0);
      }
    }
  }

  // epilogue: two 64-col passes through zs (16 hidden units each)
  _Float16* gout = args.g[z];
#pragma unroll
  for (int p = 0; p < 2; ++p) {
    __syncthreads();
    if ((wv >> 1) == p) {                   // waves owning n-half p write their acc
#pragma unroll
      for (int mi = 0; mi < 4; ++mi)
#pragma unroll
        for (int ni = 0; ni < 4; ++ni)
#pragma unroll
          for (int rr = 0; rr < 4; ++rr) {
            int row = wm + mi * 16 + ((lane >> 4) << 2) + rr;  // C/D: row=(lane>>4)*4+reg
            int col = ni * 16 + (lane & 15);                   //      col=lane&15 (0..63)
            zs[row][col] = acc[mi][ni][rr];
          }
    }
    __syncthreads();
    const int u0 = (n0 + p * 64) >> 2;      // first hidden unit of this pass
#pragma unroll
    for (int it = 0; it < 8; ++it) {
      int row = it * 16 + rbase;            // 128 rows x 16 units
      float zi = zs[row][4 * uu + 0] + bpre[p][0];
      float zj = zs[row][4 * uu + 1] + bpre[p][1];
      float zf = zs[row][4 * uu + 2] + bpre[p][2];
      float zo = zs[row][4 * uu + 3] + bpre[p][3];
      size_t co = (size_t)(m0 + row) * HID + u0 + uu;
      float cold = cpre[p][it];
      float cnew = sigm(zf + 1.0f) * cold + sigm(zi) * tanh_fast(zj);  // forget_bias=1.0
      float g = sigm(zo) * tanh_fast(cnew);
      cstate[co] = cnew;
      gout[co] = (_Float16)g;
    }
  }
}

// ---------------- projection GEMM: h = g @ WpT^T ----------------
// 64x64 tile, 256 threads, K=768, register lookahead. Chunked XCD mapping (240 = 8x30).
__global__ __launch_bounds__(256) void proj_step(ProjArgs args) {
  const int id = blockIdx.x;           // 0..239
  const int r = (id & 7) * 30 + (id >> 3);
  const int z = r / 40;
  const int q = r % 40;
  const int bx = q / 10;               // n-tile 0..3
  const int by = q % 10;               // m-tile 0..9
  if (!args.act[z]) return;

  __shared__ __align__(16) _Float16 As[64][72];
  __shared__ __align__(16) _Float16 Bs[64][72];

  const _Float16* A = args.G[z];
  const _Float16* B = args.Wp[z];
  const int n0 = bx * 64;
  const int m0 = by * 64;
  const int tid = threadIdx.x;
  const int lane = tid & 63;
  const int wv = tid >> 6;
  const int wm = (wv & 1) * 32;
  const int wn = (wv >> 1) * 32;

  f4 acc[2][2] = {};
  const int lr = tid >> 3;
  const int lkg = (tid & 7) * 8;

  // prologue: stage k0=0
  h8 av0 = *(const h8*)(A + (size_t)(m0 + lr) * HID + lkg);
  h8 av1 = *(const h8*)(A + (size_t)(m0 + lr + 32) * HID + lkg);
  h8 bv0 = *(const h8*)(B + (size_t)(n0 + lr) * HID + lkg);
  h8 bv1 = *(const h8*)(B + (size_t)(n0 + lr + 32) * HID + lkg);

  for (int k0 = 0; k0 < HID; k0 += 64) {
    __syncthreads();
    *(h8*)&As[lr][lkg] = av0;
    *(h8*)&As[lr + 32][lkg] = av1;
    *(h8*)&Bs[lr][lkg] = bv0;
    *(h8*)&Bs[lr + 32][lkg] = bv1;
    if (k0 + 64 < HID) {
      const int gk = k0 + 64 + lkg;
      av0 = *(const h8*)(A + (size_t)(m0 + lr) * HID + gk);
      av1 = *(const h8*)(A + (size_t)(m0 + lr + 32) * HID + gk);
      bv0 = *(const h8*)(B + (size_t)(n0 + lr) * HID + gk);
      bv1 = *(const h8*)(B + (size_t)(n0 + lr + 32) * HID + gk);
    }
    __syncthreads();
    const int mr = wm + (lane & 15);
    const int nr = wn + (lane & 15);
#pragma unroll
    for (int kk = 0; kk < 2; ++kk) {
      const int kq = ((lane >> 4) * 8) + kk * 32;
      h8 a0 = *(const h8*)&As[mr][kq];
      h8 a1 = *(const h8*)&As[mr + 16][kq];
      h8 b0 = *(const h8*)&Bs[nr][kq];
      h8 b1 = *(const h8*)&Bs[nr + 16][kq];
      acc[0][0] = __builtin_amdgcn_mfma_f32_16x16x32_f16(a0, b0, acc[0][0], 0, 0, 0);
      acc[0][1] = __builtin_amdgcn_mfma_f32_16x16x32_f16(a0, b1, acc[0][1], 0, 0, 0);
      acc[1][0] = __builtin_amdgcn_mfma_f32_16x16x32_f16(a1, b0, acc[1][0], 0, 0, 0);
      acc[1][1] = __builtin_amdgcn_mfma_f32_16x16x32_f16(a1, b1, acc[1][1], 0, 0, 0);
    }
  }

  _Float16* outp = args.out[z];
  _Float16* out2 = args.out2[z];
#pragma unroll
  for (int mi = 0; mi < 2; ++mi)
#pragma unroll
    for (int ni = 0; ni < 2; ++ni)
#pragma unroll
      for (int rr = 0; rr < 4; ++rr) {
        int row = wm + mi * 16 + ((lane >> 4) << 2) + rr;
        int col = wn + ni * 16 + (lane & 15);
        _Float16 v = (_Float16)acc[mi][ni][rr];
        size_t o = (size_t)(m0 + row) * PROJ + (n0 + col);
        outp[o] = v;
        if (out2) out2[o] = v;
      }
}

// ---------------- prep kernels ----------------
__global__ void convX(const float* __restrict__ X, _Float16* __restrict__ X16, size_t total) {
  size_t i = (size_t)blockIdx.x * 256 + threadIdx.x;
  if (i >= total) return;
  int p = (int)(i & 63);
  size_t tb = i >> 6;
  float v = (p < 40) ? X[tb * 40 + p] : 0.0f;
  X16[i] = (_Float16)v;
}

// Wk fp32 [Kin+256, 3072] -> WkT fp16 [3072][Kpad], gate-interleaved rows n'=4u+g,
// layer0 k-map: k<40 -> Wk[k]; 40..63 -> 0; 64..319 -> Wk[k-24]
__global__ void conv_wk(const float* __restrict__ Wk, _Float16* __restrict__ out,
                        int mode, int Kpad, size_t total) {
  size_t i = (size_t)blockIdx.x * 256 + threadIdx.x;
  if (i >= total) return;
  int k = (int)(i % Kpad);
  int n = (int)(i / Kpad);
  int u = n >> 2, g = n & 3;
  int col = g * HID + u;
  float v;
  if (mode == 0) {
    if (k < 40)      v = Wk[(size_t)k * NGATE + col];
    else if (k < 64) v = 0.0f;
    else             v = Wk[(size_t)(k - 24) * NGATE + col];
  } else {
    v = Wk[(size_t)k * NGATE + col];
  }
  out[i] = (_Float16)v;
}

__global__ void conv_wp(const float* __restrict__ Wp, _Float16* __restrict__ out, size_t total) {
  size_t i = (size_t)blockIdx.x * 256 + threadIdx.x;
  if (i >= total) return;
  int k = (int)(i % HID);
  int c = (int)(i / HID);
  out[i] = (_Float16)Wp[(size_t)k * PROJ + c];
}

// ---------------- readout ----------------
__global__ __launch_bounds__(256) void readout(const _Float16* __restrict__ E, float* __restrict__ out) {
  const size_t SL = (size_t)NB * PROJ;
  int b = blockIdx.x, tid = threadIdx.x;
  float v[2];
  float ss = 0.0f;
#pragma unroll
  for (int i = 0; i < 2; ++i) {
    int j = tid + i * 256;
    int d = j >> 8, c = j & 255;
    const _Float16* base = E + (size_t)d * 2 * SL;
    float a = (float)base[(size_t)b * PROJ + c];
    float zv = (float)base[SL + (size_t)b * PROJ + c];
    v[i] = 0.5f * (a + zv);
    ss += v[i] * v[i];
  }
#pragma unroll
  for (int off = 32; off; off >>= 1) ss += __shfl_down(ss, off);
  __shared__ float ps[4];
  if ((tid & 63) == 0) ps[tid >> 6] = ss;
  __syncthreads();
  float tot = ps[0] + ps[1] + ps[2] + ps[3];
  float nrm = rsqrtf(fmaxf(tot, 1e-12f));
  out[(size_t)b * 512 + tid] = v[0] * nrm;
  out[(size_t)b * 512 + tid + 256] = v[1] * nrm;
}

extern "C" void kernel_launch(void* const* d_in, const int* in_sizes, int n_in,
                              void* d_out, int out_size, void* d_ws, size_t ws_size,
                              hipStream_t stream) {
  (void)in_sizes; (void)n_in; (void)out_size; (void)ws_size;
  const float* X = (const float*)d_in[0];
  const float* Wk[2][3]; const float* Bi[2][3]; const float* Wp[2][3];
  for (int d = 0; d < 2; ++d)
    for (int l = 0; l < 3; ++l) {
      int base = 1 + d * 9 + l * 3;
      Wk[d][l] = (const float*)d_in[base];
      Bi[d][l] = (const float*)d_in[base + 1];
      Wp[d][l] = (const float*)d_in[base + 2];
    }

  char* ws = (char*)d_ws;
  size_t off = 0;
  auto alloc = [&](size_t bytes) -> void* {
    void* p = ws + off;
    off += (bytes + 255) & ~(size_t)255;
    return p;
  };

  const size_t SL = (size_t)NB * PROJ;    // halves per time-slot

  _Float16* X16 = (_Float16*)alloc((size_t)T_STEPS * NB * 64 * 2);
  _Float16* WkT[2][3];
  for (int d = 0; d < 2; ++d)
    for (int l = 0; l < 3; ++l)
      WkT[d][l] = (_Float16*)alloc((size_t)NGATE * (l == 0 ? 320 : 512) * 2);
  _Float16* WpT[2][3];
  for (int d = 0; d < 2; ++d)
    for (int l = 0; l < 3; ++l)
      WpT[d][l] = (_Float16*)alloc((size_t)PROJ * HID * 2);
  _Float16* Hbuf = (_Float16*)alloc(6UL * 4 * SL * 2);      // [l*2+d][4 slots][640][256]
  float* cst = (float*)alloc(6UL * NB * HID * 4);
  _Float16* gbuf = (_Float16*)alloc(6UL * NB * HID * 2);
  _Float16* embed = (_Float16*)alloc(4UL * SL * 2);         // [d][which][640][256]

  auto Hslot = [&](int l, int d, int slot) -> _Float16* {
    return Hbuf + (((size_t)(l * 2 + d) * 4) + slot) * SL;
  };

  // ---- prep ----
  {
    size_t tot = (size_t)T_STEPS * NB * 64;
    convX<<<dim3((unsigned)((tot + 255) / 256)), 256, 0, stream>>>(X, X16, tot);
  }
  for (int d = 0; d < 2; ++d)
    for (int l = 0; l < 3; ++l) {
      int Kpad = (l == 0) ? 320 : 512;
      size_t tot = (size_t)NGATE * Kpad;
      conv_wk<<<dim3((unsigned)((tot + 255) / 256)), 256, 0, stream>>>(
          Wk[d][l], WkT[d][l], (l == 0) ? 0 : 1, Kpad, tot);
      size_t totp = (size_t)PROJ * HID;
      conv_wp<<<dim3((unsigned)((totp + 255) / 256)), 256, 0, stream>>>(Wp[d][l], WpT[d][l], totp);
    }
  hipMemsetAsync(Hbuf, 0, 6UL * 4 * SL * 2, stream);        // zero rings (incl. h-init slots)
  hipMemsetAsync(cst, 0, 6UL * NB * HID * 4, stream);       // zero c state

  // ---- pipelined super-steps ----
  for (int s = 0; s <= 161; ++s) {
    GateArgs ga{};
    ProjArgs pa{};
    for (int l = 0; l < 3; ++l)
      for (int d = 0; d < 2; ++d) {
        int z = l * 2 + d;
        int t = s - l;                        // progress of layer l
        if (t < 0 || t > 159) { ga.act[z] = 0; pa.act[z] = 0; continue; }
        int tt = (d == 0) ? t : 159 - t;      // actual time index
        ga.act[z] = 1; pa.act[z] = 1;
        if (l == 0) {
          ga.A0[z] = X16 + (size_t)tt * NB * 64;
          ga.w0[z] = 64; ga.lda0[z] = 64; ga.K[z] = 320;
        } else {
          ga.A0[z] = Hslot(l - 1, d, (tt + 1) & 3);   // prev-layer output at time tt
          ga.w0[z] = 256; ga.lda0[z] = 256; ga.K[z] = 512;
        }
        int rdslot = (d == 0) ? (tt & 3) : ((tt + 2) & 3);
        ga.A1[z] = Hslot(l, d, rdslot);
        ga.Bw[z] = WkT[d][l];
        ga.bias[z] = Bi[d][l];
        ga.cst[z] = cst + (size_t)z * NB * HID;
        ga.g[z] = gbuf + (size_t)z * NB * HID;

        pa.G[z] = gbuf + (size_t)z * NB * HID;
        pa.Wp[z] = WpT[d][l];
        pa.out[z] = Hslot(l, d, (tt + 1) & 3);
        pa.out2[z] = nullptr;
        if (l == 2 && (tt == 0 || tt == 159))
          pa.out2[z] = embed + ((size_t)d * 2 + (tt == 0 ? 0 : 1)) * SL;
      }
    gate_step<<<dim3(720), 256, 0, stream>>>(ga);
    proj_step<<<dim3(240), 256, 0, stream>>>(pa);
  }

  readout<<<dim3(NB), 256, 0, stream>>>(embed, (float*)d_out);
}

// Round 12
// 5764.890 us; speedup vs baseline: 1.0057x; 1.0057x over previous
//
#include <hip/hip_runtime.h>

// BI-LSTM (TF LSTMCell w/ projection), T=160 B=640 F=40 HID=768 PROJ=256, 3 layers x 2 dirs.
// R17: R10 baseline (proven 5509us) + proj BK 64->192 ONLY.
// Budget (R10 vs R14 equations): step = 2F + G + P, G~14.8us (716 TF = 29% peak, near
// structural ceiling - R6/R8/R11/R12/R15/R16 all proved it insensitive to LDS/barrier/
// latency/locality tweaks), P~10.2us for 1.5 GFLOP (150 TF!), F~4.5us.
// Proj is a 12-iteration serial latency chain ({stage -> 2 barriers -> 8 MFMA} = ~2000cy
// stage+barrier vs ~40cy MFMA per iter) at ~1 block/CU (240 blocks, no overlap).
// Fix: BK=192 -> 4 iters, 8 barriers instead of 24. LDS 2x[64][200] fp16 = 51.2KB
// (<64KB static cap, 3 blocks/CU). Thread stages one row x 48 cols (6x h8, coalesced).
// Reg-lookahead kept. Gate/grids/launcher = R10 verbatim (R16 swizzle reverted).

typedef _Float16 h8 __attribute__((ext_vector_type(8)));
typedef float f4 __attribute__((ext_vector_type(4)));

#define T_STEPS 160
#define NB 640
#define HID 768
#define PROJ 256
#define NGATE 3072           // 4*HID

__device__ __forceinline__ float sigm(float x) { return 1.0f / (1.0f + __expf(-x)); }
__device__ __forceinline__ float tanh_fast(float x) { return 2.0f / (1.0f + __expf(-2.0f * x)) - 1.0f; }

struct GateArgs {
  const _Float16* A0[6];   // x-part source (X16 for l=0, prev-layer ring slot otherwise)
  const _Float16* A1[6];   // own h ring slot (h_{t-1} fw / h_{t+1} bw)
  const _Float16* Bw[6];   // WkT, gate-interleaved [3072][Kpad]
  const float*    bias[6];
  float*          cst[6];
  _Float16*       g[6];
  int w0[6];
  int lda0[6];
  int K[6];
  int act[6];
};

struct ProjArgs {
  const _Float16* G[6];    // [640][768] fp16
  const _Float16* Wp[6];   // [256][768] fp16 (B^T)
  _Float16* out[6];        // own ring write slot
  _Float16* out2[6];       // optional embed capture (layer 2, t in {0,159})
  int act[6];
};

// ---------------- gate GEMM: z = [x,h] @ WkT^T, fused bias+gates+c-update -> g ----------------
__global__ __launch_bounds__(256, 3) void gate_step(GateArgs args) {
  const int z = blockIdx.z;
  if (!args.act[z]) return;

  __shared__ __align__(16) char sm[36864];       // As 18KB | Bs 18KB; epilogue overlays zs
  _Float16 (*As)[72] = (_Float16(*)[72])sm;      // [128][72]
  _Float16 (*Bs)[72] = (_Float16(*)[72])(sm + 18432);
  float (*zs)[65] = (float(*)[65])sm;            // [128][65] f32 = 33.3KB

  const _Float16* A0 = args.A0[z];
  const _Float16* A1 = args.A1[z];
  const _Float16* Bw = args.Bw[z];
  const int w0 = args.w0[z], lda0 = args.lda0[z], K = args.K[z];
  const int n0 = blockIdx.x * 128;
  const int m0 = blockIdx.y * 128;
  const int tid = threadIdx.x;
  const int lane = tid & 63;
  const int wv = tid >> 6;         // 0..3
  const int wm = (wv & 1) * 64;    // wave covers rows [wm, wm+64), cols [wn, wn+64)
  const int wn = (wv >> 1) * 64;

  // ---- epilogue-operand prefetch (addresses known from blockIdx/tid alone) ----
  const float* bias = args.bias[z];
  float* cstate = args.cst[z];
  const int uu = tid & 15;
  const int rbase = tid >> 4;
  float cpre[2][8];
  float bpre[2][4];
#pragma unroll
  for (int p = 0; p < 2; ++p) {
    const int u0 = (n0 + p * 64) >> 2;
#pragma unroll
    for (int gg = 0; gg < 4; ++gg)
      bpre[p][gg] = bias[gg * HID + u0 + uu];
#pragma unroll
    for (int it = 0; it < 8; ++it)
      cpre[p][it] = cstate[(size_t)(m0 + it * 16 + rbase) * HID + u0 + uu];
  }

  f4 acc[4][4] = {};

  const int lr = tid >> 3;          // 0..31 (handles rows lr + 32*r)
  const int lkg = (tid & 7) * 8;    // k-group 0,8,..,56

  // ---- prologue: stage k0=0 into registers ----
  h8 av[4], bv[4];
  {
    const int gk = lkg;
    if (gk < w0) {
#pragma unroll
      for (int r = 0; r < 4; ++r)
        av[r] = *(const h8*)(A0 + (size_t)(m0 + lr + 32 * r) * lda0 + gk);
    } else {
#pragma unroll
      for (int r = 0; r < 4; ++r)
        av[r] = *(const h8*)(A1 + (size_t)(m0 + lr + 32 * r) * 256 + (gk - w0));
    }
#pragma unroll
    for (int r = 0; r < 4; ++r)
      bv[r] = *(const h8*)(Bw + (size_t)(n0 + lr + 32 * r) * K + gk);
  }

  for (int k0 = 0; k0 < K; k0 += 64) {
    __syncthreads();                 // prior iter's LDS readers done
#pragma unroll
    for (int r = 0; r < 4; ++r) {    // vmcnt wait here is for regs staged LAST iter (hidden)
      *(h8*)&As[lr + 32 * r][lkg] = av[r];
      *(h8*)&Bs[lr + 32 * r][lkg] = bv[r];
    }
    // issue NEXT iter's loads now; latency hides under this iter's MFMAs
    if (k0 + 64 < K) {
      const int gk = k0 + 64 + lkg;
      if (gk < w0) {
#pragma unroll
        for (int r = 0; r < 4; ++r)
          av[r] = *(const h8*)(A0 + (size_t)(m0 + lr + 32 * r) * lda0 + gk);
      } else {
#pragma unroll
        for (int r = 0; r < 4; ++r)
          av[r] = *(const h8*)(A1 + (size_t)(m0 + lr + 32 * r) * 256 + (gk - w0));
      }
#pragma unroll
      for (int r = 0; r < 4; ++r)
        bv[r] = *(const h8*)(Bw + (size_t)(n0 + lr + 32 * r) * K + gk);
    }
    __syncthreads();
#pragma unroll
    for (int kk = 0; kk < 2; ++kk) {
      const int kq = ((lane >> 4) * 8) + kk * 32;
      h8 bf[4];
#pragma unroll
      for (int j = 0; j < 4; ++j)
        bf[j] = *(const h8*)&Bs[wn + (lane & 15) + 16 * j][kq];
#pragma unroll
      for (int i = 0; i < 4; ++i) {
        h8 af = *(const h8*)&As[wm + (lane & 15) + 16 * i][kq];
#pragma unroll
        for (int j = 0; j < 4; ++j)
          acc[i][j] = __builtin_amdgcn_mfma_f32_16x16x32_f16(af, bf[j], acc[i][j], 0, 0, 0);
      }
    }
  }

  // epilogue: two 64-col passes through zs (16 hidden units each)
  _Float16* gout = args.g[z];
#pragma unroll
  for (int p = 0; p < 2; ++p) {
    __syncthreads();
    if ((wv >> 1) == p) {                   // waves owning n-half p write their acc
#pragma unroll
      for (int mi = 0; mi < 4; ++mi)
#pragma unroll
        for (int ni = 0; ni < 4; ++ni)
#pragma unroll
          for (int r = 0; r < 4; ++r) {
            int row = wm + mi * 16 + ((lane >> 4) << 2) + r;  // C/D: row=(lane>>4)*4+reg
            int col = ni * 16 + (lane & 15);                  //      col=lane&15 (0..63)
            zs[row][col] = acc[mi][ni][r];
          }
    }
    __syncthreads();
    const int u0 = (n0 + p * 64) >> 2;      // first hidden unit of this pass
#pragma unroll
    for (int it = 0; it < 8; ++it) {
      int row = it * 16 + rbase;            // 128 rows x 16 units
      float zi = zs[row][4 * uu + 0] + bpre[p][0];
      float zj = zs[row][4 * uu + 1] + bpre[p][1];
      float zf = zs[row][4 * uu + 2] + bpre[p][2];
      float zo = zs[row][4 * uu + 3] + bpre[p][3];
      size_t co = (size_t)(m0 + row) * HID + u0 + uu;
      float cold = cpre[p][it];
      float cnew = sigm(zf + 1.0f) * cold + sigm(zi) * tanh_fast(zj);  // forget_bias=1.0
      float g = sigm(zo) * tanh_fast(cnew);
      cstate[co] = cnew;
      gout[co] = (_Float16)g;
    }
  }
}

// ---------------- projection GEMM: h = g @ WpT^T ----------------
// 64x64 tile, 256 threads, K=768, BK=192 (4 iters, 8 barriers vs 24), reg lookahead.
// LDS 2 x [64][200] fp16 = 51.2KB. Each thread stages one row x 48 cols (6 x h8).
__global__ __launch_bounds__(256) void proj_step(ProjArgs args) {
  const int z = blockIdx.z;
  if (!args.act[z]) return;

  __shared__ __align__(16) _Float16 As[64][200];
  __shared__ __align__(16) _Float16 Bs[64][200];

  const _Float16* A = args.G[z];
  const _Float16* B = args.Wp[z];
  const int n0 = blockIdx.x * 64;
  const int m0 = blockIdx.y * 64;
  const int tid = threadIdx.x;
  const int lane = tid & 63;
  const int wv = tid >> 6;
  const int wm = (wv & 1) * 32;
  const int wn = (wv >> 1) * 32;

  f4 acc[2][2] = {};
  const int lr = tid >> 2;          // one row per thread (0..63)
  const int lkg = (tid & 3) * 48;   // 48-col group per thread

  // prologue: stage k0=0
  h8 av[6], bv[6];
#pragma unroll
  for (int j = 0; j < 6; ++j) {
    av[j] = *(const h8*)(A + (size_t)(m0 + lr) * HID + lkg + 8 * j);
    bv[j] = *(const h8*)(B + (size_t)(n0 + lr) * HID + lkg + 8 * j);
  }

  for (int k0 = 0; k0 < HID; k0 += 192) {
    __syncthreads();                 // prior iter's frag reads complete
#pragma unroll
    for (int j = 0; j < 6; ++j) {    // vmcnt wait = last iter's loads (hidden)
      *(h8*)&As[lr][lkg + 8 * j] = av[j];
      *(h8*)&Bs[lr][lkg + 8 * j] = bv[j];
    }
    if (k0 + 192 < HID) {            // next iter's loads hide under this iter's MFMAs
      const int gk = k0 + 192 + lkg;
#pragma unroll
      for (int j = 0; j < 6; ++j) {
        av[j] = *(const h8*)(A + (size_t)(m0 + lr) * HID + gk + 8 * j);
        bv[j] = *(const h8*)(B + (size_t)(n0 + lr) * HID + gk + 8 * j);
      }
    }
    __syncthreads();
    const int mr = wm + (lane & 15);
    const int nr = wn + (lane & 15);
#pragma unroll
    for (int kk = 0; kk < 6; ++kk) {
      const int kq = ((lane >> 4) * 8) + kk * 32;
      h8 a0 = *(const h8*)&As[mr][kq];
      h8 a1 = *(const h8*)&As[mr + 16][kq];
      h8 b0 = *(const h8*)&Bs[nr][kq];
      h8 b1 = *(const h8*)&Bs[nr + 16][kq];
      acc[0][0] = __builtin_amdgcn_mfma_f32_16x16x32_f16(a0, b0, acc[0][0], 0, 0, 0);
      acc[0][1] = __builtin_amdgcn_mfma_f32_16x16x32_f16(a0, b1, acc[0][1], 0, 0, 0);
      acc[1][0] = __builtin_amdgcn_mfma_f32_16x16x32_f16(a1, b0, acc[1][0], 0, 0, 0);
      acc[1][1] = __builtin_amdgcn_mfma_f32_16x16x32_f16(a1, b1, acc[1][1], 0, 0, 0);
    }
  }

  _Float16* outp = args.out[z];
  _Float16* out2 = args.out2[z];
#pragma unroll
  for (int mi = 0; mi < 2; ++mi)
#pragma unroll
    for (int ni = 0; ni < 2; ++ni)
#pragma unroll
      for (int r = 0; r < 4; ++r) {
        int row = wm + mi * 16 + ((lane >> 4) << 2) + r;
        int col = wn + ni * 16 + (lane & 15);
        _Float16 v = (_Float16)acc[mi][ni][r];
        size_t o = (size_t)(m0 + row) * PROJ + (n0 + col);
        outp[o] = v;
        if (out2) out2[o] = v;
      }
}

// ---------------- prep kernels ----------------
__global__ void convX(const float* __restrict__ X, _Float16* __restrict__ X16, size_t total) {
  size_t i = (size_t)blockIdx.x * 256 + threadIdx.x;
  if (i >= total) return;
  int p = (int)(i & 63);
  size_t tb = i >> 6;
  float v = (p < 40) ? X[tb * 40 + p] : 0.0f;
  X16[i] = (_Float16)v;
}

// Wk fp32 [Kin+256, 3072] -> WkT fp16 [3072][Kpad], gate-interleaved rows n'=4u+g,
// layer0 k-map: k<40 -> Wk[k]; 40..63 -> 0; 64..319 -> Wk[k-24]
__global__ void conv_wk(const float* __restrict__ Wk, _Float16* __restrict__ out,
                        int mode, int Kpad, size_t total) {
  size_t i = (size_t)blockIdx.x * 256 + threadIdx.x;
  if (i >= total) return;
  int k = (int)(i % Kpad);
  int n = (int)(i / Kpad);
  int u = n >> 2, g = n & 3;
  int col = g * HID + u;
  float v;
  if (mode == 0) {
    if (k < 40)      v = Wk[(size_t)k * NGATE + col];
    else if (k < 64) v = 0.0f;
    else             v = Wk[(size_t)(k - 24) * NGATE + col];
  } else {
    v = Wk[(size_t)k * NGATE + col];
  }
  out[i] = (_Float16)v;
}

__global__ void conv_wp(const float* __restrict__ Wp, _Float16* __restrict__ out, size_t total) {
  size_t i = (size_t)blockIdx.x * 256 + threadIdx.x;
  if (i >= total) return;
  int k = (int)(i % HID);
  int c = (int)(i / HID);
  out[i] = (_Float16)Wp[(size_t)k * PROJ + c];
}

// ---------------- readout ----------------
__global__ __launch_bounds__(256) void readout(const _Float16* __restrict__ E, float* __restrict__ out) {
  const size_t SL = (size_t)NB * PROJ;
  int b = blockIdx.x, tid = threadIdx.x;
  float v[2];
  float ss = 0.0f;
#pragma unroll
  for (int i = 0; i < 2; ++i) {
    int j = tid + i * 256;
    int d = j >> 8, c = j & 255;
    const _Float16* base = E + (size_t)d * 2 * SL;
    float a = (float)base[(size_t)b * PROJ + c];
    float zv = (float)base[SL + (size_t)b * PROJ + c];
    v[i] = 0.5f * (a + zv);
    ss += v[i] * v[i];
  }
#pragma unroll
  for (int off = 32; off; off >>= 1) ss += __shfl_down(ss, off);
  __shared__ float ps[4];
  if ((tid & 63) == 0) ps[tid >> 6] = ss;
  __syncthreads();
  float tot = ps[0] + ps[1] + ps[2] + ps[3];
  float nrm = rsqrtf(fmaxf(tot, 1e-12f));
  out[(size_t)b * 512 + tid] = v[0] * nrm;
  out[(size_t)b * 512 + tid + 256] = v[1] * nrm;
}

extern "C" void kernel_launch(void* const* d_in, const int* in_sizes, int n_in,
                              void* d_out, int out_size, void* d_ws, size_t ws_size,
                              hipStream_t stream) {
  (void)in_sizes; (void)n_in; (void)out_size; (void)ws_size;
  const float* X = (const float*)d_in[0];
  const float* Wk[2][3]; const float* Bi[2][3]; const float* Wp[2][3];
  for (int d = 0; d < 2; ++d)
    for (int l = 0; l < 3; ++l) {
      int base = 1 + d * 9 + l * 3;
      Wk[d][l] = (const float*)d_in[base];
      Bi[d][l] = (const float*)d_in[base + 1];
      Wp[d][l] = (const float*)d_in[base + 2];
    }

  char* ws = (char*)d_ws;
  size_t off = 0;
  auto alloc = [&](size_t bytes) -> void* {
    void* p = ws + off;
    off += (bytes + 255) & ~(size_t)255;
    return p;
  };

  const size_t SL = (size_t)NB * PROJ;    // halves per time-slot

  _Float16* X16 = (_Float16*)alloc((size_t)T_STEPS * NB * 64 * 2);
  _Float16* WkT[2][3];
  for (int d = 0; d < 2; ++d)
    for (int l = 0; l < 3; ++l)
      WkT[d][l] = (_Float16*)alloc((size_t)NGATE * (l == 0 ? 320 : 512) * 2);
  _Float16* WpT[2][3];
  for (int d = 0; d < 2; ++d)
    for (int l = 0; l < 3; ++l)
      WpT[d][l] = (_Float16*)alloc((size_t)PROJ * HID * 2);
  _Float16* Hbuf = (_Float16*)alloc(6UL * 4 * SL * 2);      // [l*2+d][4 slots][640][256]
  float* cst = (float*)alloc(6UL * NB * HID * 4);
  _Float16* gbuf = (_Float16*)alloc(6UL * NB * HID * 2);
  _Float16* embed = (_Float16*)alloc(4UL * SL * 2);         // [d][which][640][256]

  auto Hslot = [&](int l, int d, int slot) -> _Float16* {
    return Hbuf + (((size_t)(l * 2 + d) * 4) + slot) * SL;
  };

  // ---- prep ----
  {
    size_t tot = (size_t)T_STEPS * NB * 64;
    convX<<<dim3((unsigned)((tot + 255) / 256)), 256, 0, stream>>>(X, X16, tot);
  }
  for (int d = 0; d < 2; ++d)
    for (int l = 0; l < 3; ++l) {
      int Kpad = (l == 0) ? 320 : 512;
      size_t tot = (size_t)NGATE * Kpad;
      conv_wk<<<dim3((unsigned)((tot + 255) / 256)), 256, 0, stream>>>(
          Wk[d][l], WkT[d][l], (l == 0) ? 0 : 1, Kpad, tot);
      size_t totp = (size_t)PROJ * HID;
      conv_wp<<<dim3((unsigned)((totp + 255) / 256)), 256, 0, stream>>>(Wp[d][l], WpT[d][l], totp);
    }
  hipMemsetAsync(Hbuf, 0, 6UL * 4 * SL * 2, stream);        // zero rings (incl. h-init slots)
  hipMemsetAsync(cst, 0, 6UL * NB * HID * 4, stream);       // zero c state

  // ---- pipelined super-steps ----
  for (int s = 0; s <= 161; ++s) {
    GateArgs ga{};
    ProjArgs pa{};
    for (int l = 0; l < 3; ++l)
      for (int d = 0; d < 2; ++d) {
        int z = l * 2 + d;
        int t = s - l;                        // progress of layer l
        if (t < 0 || t > 159) { ga.act[z] = 0; pa.act[z] = 0; continue; }
        int tt = (d == 0) ? t : 159 - t;      // actual time index
        ga.act[z] = 1; pa.act[z] = 1;
        if (l == 0) {
          ga.A0[z] = X16 + (size_t)tt * NB * 64;
          ga.w0[z] = 64; ga.lda0[z] = 64; ga.K[z] = 320;
        } else {
          ga.A0[z] = Hslot(l - 1, d, (tt + 1) & 3);   // prev-layer output at time tt
          ga.w0[z] = 256; ga.lda0[z] = 256; ga.K[z] = 512;
        }
        int rdslot = (d == 0) ? (tt & 3) : ((tt + 2) & 3);
        ga.A1[z] = Hslot(l, d, rdslot);
        ga.Bw[z] = WkT[d][l];
        ga.bias[z] = Bi[d][l];
        ga.cst[z] = cst + (size_t)z * NB * HID;
        ga.g[z] = gbuf + (size_t)z * NB * HID;

        pa.G[z] = gbuf + (size_t)z * NB * HID;
        pa.Wp[z] = WpT[d][l];
        pa.out[z] = Hslot(l, d, (tt + 1) & 3);
        pa.out2[z] = nullptr;
        if (l == 2 && (tt == 0 || tt == 159))
          pa.out2[z] = embed + ((size_t)d * 2 + (tt == 0 ? 0 : 1)) * SL;
      }
    gate_step<<<dim3(24, 5, 6), 256, 0, stream>>>(ga);
    proj_step<<<dim3(4, 10, 6), 256, 0, stream>>>(pa);
  }

  readout<<<dim3(NB), 256, 0, stream>>>(embed, (float*)d_out);
}